// Round 1
// baseline (498.104 us; speedup 1.0000x reference)
//
#include <hip/hip_runtime.h>
#include <math.h>

// ---------------------------------------------------------------------------
// DeepFM on MI355X, round 4.
// Pipeline: [prep: wtrans x3 + gather+FM] -> [gemm_pipe<256,256> GEMM1]
//           -> [gemm_pipe<128,256> GEMM2] -> [GEMM3 64x256 fused head]
// gemm_pipe: BK=32, 4 LDS buffers, prefetch distance 3, counted vmcnt
// (never 0 in steady state), raw s_barrier (no vmcnt(0) drain), LDS slot-XOR
// swizzle applied on BOTH sides (pre-swizzled global source for
// global_load_lds + swizzled ds_read), setprio around MFMA, bijective XCD
// blockIdx swizzle (grid % 8 == 0).
// Workspace layout (bytes):
//   h0  @ 0        : bf16 [16384 x 896] (29,360,128); reused for h2 bf16 [16384 x 512]
//   h1  @ 29360128 : bf16 [16384 x 1024] (33,554,432)
//   Wt0 @ 62914560 : bf16 [1024 x 896]
//   Wt1 @ 64749568 : bf16 [512 x 1024]
//   Wt2 @ 65798144 : bf16 [256 x 512]
//   lg  @ 66060288 : f32 [16384]
// ---------------------------------------------------------------------------

typedef __attribute__((ext_vector_type(8))) short shortx8;
typedef __attribute__((ext_vector_type(4))) float floatx4;

#define AS1 __attribute__((address_space(1)))
#define AS3 __attribute__((address_space(3)))

__device__ __forceinline__ void load_lds_16(const void* g, void* l) {
    __builtin_amdgcn_global_load_lds((AS1 void*)g, (AS3 void*)l, 16, 0, 0);
}

__device__ __forceinline__ unsigned short f2bf(float x) {
    union { float f; unsigned int u; } v; v.f = x;
    unsigned int r = v.u + 0x7fffu + ((v.u >> 16) & 1u);
    return (unsigned short)(r >> 16);
}

template<int N>
__device__ __forceinline__ void waitvm() {
    asm volatile("s_waitcnt vmcnt(%0)" :: "n"(N) : "memory");
}

// Raw barrier: no implicit vmcnt(0)/lgkmcnt(0) drain (unlike __syncthreads),
// with compiler-level memory fences so LDS/global ops cannot cross it.
__device__ __forceinline__ void bar() {
    asm volatile("" ::: "memory");
    __builtin_amdgcn_s_barrier();
    asm volatile("" ::: "memory");
}

// ---------------------------------------------------------------------------
// Prep kernel: blockIdx ranges dispatch to gather+FM or one of 3 wtrans tiles.
//   [0, 4096)            : gather+FM (wave per batch row)
//   [4096, 4992)         : wtrans W0 -> Wt0 [1024 x 896], grid 28 x 32
//   [4992, 5504)         : wtrans W1 -> Wt1 [512 x 1024], grid 32 x 16
//   [5504, 5632)         : wtrans W2 -> Wt2 [256 x 512],  grid 16 x 8
// ---------------------------------------------------------------------------
__device__ __forceinline__
void wtrans_tile(const float* __restrict__ W, unsigned short* __restrict__ Wt,
                 int K, int N, int Kpad, int bx, int by, int tid)
{
    __shared__ float tile[32][33];
    const int k0 = bx * 32, n0 = by * 32;
    const int tx = tid & 31, ty = tid >> 5;
#pragma unroll
    for (int i = 0; i < 32; i += 8) {
        int k = k0 + ty + i;
        tile[ty + i][tx] = (k < K) ? W[(size_t)k * N + (n0 + tx)] : 0.f;
    }
    __syncthreads();
#pragma unroll
    for (int i = 0; i < 32; i += 8) {
        int n = n0 + ty + i, kk = k0 + tx;
        Wt[(size_t)n * Kpad + kk] = f2bf(tile[tx][ty + i]);
    }
}

__global__ __launch_bounds__(256)
void prep(const int* __restrict__ xs, const float* __restrict__ xd,
          const float* __restrict__ emb, const float* __restrict__ lint,
          const float* __restrict__ W0, const float* __restrict__ W1,
          const float* __restrict__ W2,
          unsigned short* __restrict__ h0, float* __restrict__ lg,
          unsigned short* __restrict__ Wt0, unsigned short* __restrict__ Wt1,
          unsigned short* __restrict__ Wt2)
{
    const int bid = blockIdx.x;
    const int tid = threadIdx.x;

    if (bid >= 4096) {
        int t = bid - 4096;
        if (t < 896)       wtrans_tile(W0, Wt0, 845, 1024, 896, t % 28, t / 28, tid);
        else if (t < 1408) wtrans_tile(W1, Wt1, 1024, 512, 1024, (t - 896) % 32, (t - 896) / 32, tid);
        else               wtrans_tile(W2, Wt2, 512, 256, 512, (t - 1408) % 16, (t - 1408) / 16, tid);
        return;
    }

    const int lane = tid & 63;
    const int wave = tid >> 6;
    const int b = bid * 4 + wave;

    int idx = 0; float linv = 0.f;
    if (lane < 26) {
        idx = xs[b * 26 + lane];
        linv = lint[(size_t)lane * 100000 + idx];
    }
    const int d = lane & 31;
    const int half = lane >> 5;
    float s = 0.f, sq = 0.f;
    unsigned short* hrow = h0 + (size_t)b * 896;
#pragma unroll
    for (int it = 0; it < 13; ++it) {
        int f = it * 2 + half;
        int fidx = __shfl(idx, f);
        float v = emb[((size_t)f * 100000 + (size_t)fidx) * 32 + d];
        s += v; sq += v * v;
        hrow[f * 32 + d] = f2bf(v);
    }
    s += __shfl_xor(s, 32);
    float t = 0.25f * s * s - 0.5f * sq + linv;
#pragma unroll
    for (int off = 32; off >= 1; off >>= 1) t += __shfl_xor(t, off);
    if (lane == 0) lg[b] = t;

    // cols 832..844 dense, 845..895 zero: lanes 13..63 cover 845..895 exactly
    if (lane < 13) hrow[832 + lane] = f2bf(xd[b * 13 + lane]);
    else           hrow[832 + lane] = 0;
}

// ---------------------------------------------------------------------------
// Deep-pipelined GEMM: Y[M,N] = relu(X@Wt^T + bias), bf16 in/out, f32 acc.
// BK=32. 512 threads = 8 waves in a 2(M) x 4(N) grid; per-wave tile
// (BM/2) x (BN/4); per K-tile per wave: MR*NR MFMA 16x16x32.
// 4 LDS buffers (tile t -> buf t&3), prefetch distance 3:
//   iter t: STAGE(t+3) -> waitvm(3*LPT) [retires tile t only] -> bar()
//           -> ds_read frags (swizzled) -> MFMA (setprio 1) -> bar()
// Buffer-liveness ledger: reads of buf c end at iter t's trailing bar();
// buf c is next written by STAGE(t+4) at iter t+1 (one barrier apart). Loads
// retire in issue order, so vmcnt(3*LPT) == "tile t complete" (m135).
// LDS swizzle: 64B rows of 4x16B slots; stored slot = logical ^ (row&3).
// Applied as pre-swizzled GLOBAL source (global_load_lds writes linearly)
// + same XOR on the ds_read address (involution, both sides).
// ---------------------------------------------------------------------------
template<int BM, int BN>
__global__ __launch_bounds__(512, 2)
void gemm_pipe(const unsigned short* __restrict__ X,
               const unsigned short* __restrict__ Wt,
               const float* __restrict__ bias,
               unsigned short* __restrict__ Y,
               int M, int N, int K, int nby)
{
    constexpr int CA  = BM / 128;       // A staging loads/thread/tile
    constexpr int CB  = BN / 128;       // B staging loads/thread/tile
    constexpr int LPT = CA + CB;        // loads/thread/tile
    constexpr int MR  = BM / 32;        // 16-row M frags per wave
    constexpr int NR  = BN / 64;        // 16-col N frags per wave

    __shared__ alignas(16) unsigned short As[4][BM * 32];
    __shared__ alignas(16) unsigned short Bs[4][BN * 32];

    const int tid   = threadIdx.x;
    const int lane  = tid & 63;
    const int wave  = tid >> 6;
    const int lrow  = lane & 15;
    const int lquad = lane >> 4;
    const int wm = (wave >> 2) * (BM / 2);
    const int wn = (wave & 3) * (BN / 4);

    // bijective XCD swizzle (gridDim.x % 8 == 0); consecutive swz share bx
    // (A panel) and cycle by (B panels) within an XCD's chunk.
    const int nwg = gridDim.x;
    const int bid = blockIdx.x;
    const int swz = (bid & 7) * (nwg >> 3) + (bid >> 3);
    const int bx = swz / nby, by = swz % nby;
    const int bm = bx * BM, bn = by * BN;

    floatx4 acc[MR][NR];
    const floatx4 z4 = {0.f, 0.f, 0.f, 0.f};
#pragma unroll
    for (int i = 0; i < MR; ++i)
#pragma unroll
        for (int j = 0; j < NR; ++j) acc[i][j] = z4;

    const int NT = K >> 5;   // K-tiles of 32

    auto STAGE = [&](int tt) {
        const int k0 = tt << 5;
        unsigned short* a_dst = As[tt & 3];
        unsigned short* b_dst = Bs[tt & 3];
#pragma unroll
        for (int q = 0; q < CA; ++q) {
            int c = tid + q * 512;
            int row = c >> 2, sl = c & 3;
            load_lds_16(X + (size_t)(bm + row) * K + (k0 + ((sl ^ (row & 3)) << 3)),
                        a_dst + c * 8);
        }
#pragma unroll
        for (int q = 0; q < CB; ++q) {
            int c = tid + q * 512;
            int row = c >> 2, sl = c & 3;
            load_lds_16(Wt + (size_t)(bn + row) * K + (k0 + ((sl ^ (row & 3)) << 3)),
                        b_dst + c * 8);
        }
    };

    // prologue: tiles 0..2 in flight
    STAGE(0); STAGE(1); STAGE(2);

    // swizzled ds_read base offsets (elements); (wm|wn|i*16) & 3 == 0
    const int abase = (wm + lrow) * 32 + ((lquad ^ (lrow & 3)) << 3);
    const int bbase = (wn + lrow) * 32 + ((lquad ^ (lrow & 3)) << 3);

    for (int t = 0; t < NT; ++t) {
        const int cur = t & 3;
        if (t + 3 < NT)      { STAGE(t + 3); waitvm<3 * LPT>(); }
        else if (t + 2 < NT) waitvm<2 * LPT>();
        else if (t + 1 < NT) waitvm<LPT>();
        else                 waitvm<0>();
        bar();

        shortx8 a[MR], b[NR];
#pragma unroll
        for (int i = 0; i < MR; ++i)
            a[i] = *(const shortx8*)(&As[cur][abase + i * 512]);
#pragma unroll
        for (int j = 0; j < NR; ++j)
            b[j] = *(const shortx8*)(&Bs[cur][bbase + j * 512]);

        __builtin_amdgcn_s_setprio(1);
#pragma unroll
        for (int i = 0; i < MR; ++i)
#pragma unroll
            for (int j = 0; j < NR; ++j)
                acc[i][j] = __builtin_amdgcn_mfma_f32_16x16x32_bf16(a[i], b[j], acc[i][j], 0, 0, 0);
        __builtin_amdgcn_s_setprio(0);
        bar();
    }

#pragma unroll
    for (int i = 0; i < MR; ++i) {
        const int row = bm + wm + i * 16 + lquad * 4;
#pragma unroll
        for (int j = 0; j < NR; ++j) {
            const int col = bn + wn + j * 16 + lrow;
            const float bv = bias[col];
#pragma unroll
            for (int r = 0; r < 4; ++r) {
                float v = fmaxf(acc[i][j][r] + bv, 0.f);
                Y[(size_t)(row + r) * N + col] = f2bf(v);
            }
        }
    }
}

// ---------------------------------------------------------------------------
// GEMM3 fused with output head. Block: 64 rows x full N=256 (K=512, BK=32).
// ---------------------------------------------------------------------------
__global__ __launch_bounds__(256)
void gemm3_final(const unsigned short* __restrict__ X,   // h2 [16384 x 512] bf16
                 const unsigned short* __restrict__ Wt,  // Wt2 [256 x 512] bf16
                 const float* __restrict__ bias,         // b2 [256]
                 const float* __restrict__ Wo,           // [256]
                 const float* __restrict__ bo,           // [1]
                 const float* __restrict__ lg,           // [16384]
                 float* __restrict__ out)                // [16384]
{
    const int K = 512;
    __shared__ alignas(16) unsigned short As[64 * 32];
    __shared__ alignas(16) unsigned short Bs[256 * 32];
    __shared__ float red[4][64];

    const int tid  = threadIdx.x;
    const int lane = tid & 63;
    const int wave = tid >> 6;
    const int bm = blockIdx.x * 64;
    const int wn = wave * 64;
    const int lrow  = lane & 15;
    const int lquad = lane >> 4;

    floatx4 acc[4][4];
    const floatx4 z4 = {0.f, 0.f, 0.f, 0.f};
#pragma unroll
    for (int i = 0; i < 4; ++i)
#pragma unroll
        for (int j = 0; j < 4; ++j) acc[i][j] = z4;

    const int ar = tid >> 2, akp = (tid & 3) << 3;

    for (int k0 = 0; k0 < K; k0 += 32) {
        load_lds_16(X + (size_t)(bm + ar) * K + (k0 + akp), As + (size_t)tid * 8);
#pragma unroll
        for (int q = 0; q < 4; ++q) {
            int c = tid + q * 256;
            load_lds_16(Wt + (size_t)(c >> 2) * K + (k0 + akp), Bs + (size_t)c * 8);
        }
        __syncthreads();

        shortx8 a[4], b[4];
#pragma unroll
        for (int i = 0; i < 4; ++i)
            a[i] = *(const shortx8*)(As + (i * 16 + lrow) * 32 + lquad * 8);
#pragma unroll
        for (int j = 0; j < 4; ++j)
            b[j] = *(const shortx8*)(Bs + (wn + j * 16 + lrow) * 32 + lquad * 8);
#pragma unroll
        for (int i = 0; i < 4; ++i)
#pragma unroll
            for (int j = 0; j < 4; ++j)
                acc[i][j] = __builtin_amdgcn_mfma_f32_16x16x32_bf16(a[i], b[j], acc[i][j], 0, 0, 0);
        __syncthreads();
    }

    float bv[4], wv[4];
#pragma unroll
    for (int j = 0; j < 4; ++j) {
        int col = wn + j * 16 + lrow;
        bv[j] = bias[col];
        wv[j] = Wo[col];
    }
#pragma unroll
    for (int i = 0; i < 4; ++i) {
#pragma unroll
        for (int r = 0; r < 4; ++r) {
            float p = 0.f;
#pragma unroll
            for (int j = 0; j < 4; ++j) {
                float v = fmaxf(acc[i][j][r] + bv[j], 0.f);
                p += v * wv[j];
            }
            p += __shfl_xor(p, 1);
            p += __shfl_xor(p, 2);
            p += __shfl_xor(p, 4);
            p += __shfl_xor(p, 8);
            if (lrow == 0) red[wave][i * 16 + lquad * 4 + r] = p;
        }
    }
    __syncthreads();
    if (tid < 64) {
        float s = red[0][tid] + red[1][tid] + red[2][tid] + red[3][tid];
        float x = s + bo[0] + lg[bm + tid];
        out[bm + tid] = 1.f / (1.f + expf(-x));
    }
}

extern "C" void kernel_launch(void* const* d_in, const int* in_sizes, int n_in,
                              void* d_out, int out_size, void* d_ws, size_t ws_size,
                              hipStream_t stream)
{
    const int*   xs = (const int*)d_in[0];
    const float* xd = (const float*)d_in[1];
    const float* em = (const float*)d_in[2];
    const float* li = (const float*)d_in[3];
    const float* W0 = (const float*)d_in[4];
    const float* b0 = (const float*)d_in[5];
    const float* W1 = (const float*)d_in[6];
    const float* b1 = (const float*)d_in[7];
    const float* W2 = (const float*)d_in[8];
    const float* b2 = (const float*)d_in[9];
    const float* Wo = (const float*)d_in[10];
    const float* bo = (const float*)d_in[11];
    float* out = (float*)d_out;

    char* ws = (char*)d_ws;
    unsigned short* h0  = (unsigned short*)(ws);             // 16384x896 bf16
    unsigned short* h1  = (unsigned short*)(ws + 29360128);  // 16384x1024 bf16
    unsigned short* h2  = (unsigned short*)(ws);             // reuse: 16384x512 bf16
    unsigned short* Wt0 = (unsigned short*)(ws + 62914560);  // 1024x896 bf16
    unsigned short* Wt1 = (unsigned short*)(ws + 64749568);  // 512x1024 bf16
    unsigned short* Wt2 = (unsigned short*)(ws + 65798144);  // 256x512 bf16
    float*          lg  = (float*)(ws + 66060288);           // 16384 f32

    prep<<<5632, 256, 0, stream>>>(xs, xd, em, li, W0, W1, W2, h0, lg, Wt0, Wt1, Wt2);

    // GEMM1: 16384x1024, K=896 -> 64x4 = 256 blocks (1/CU, 128 KB LDS)
    gemm_pipe<256, 256><<<256, 512, 0, stream>>>(h0, Wt0, b0, h1, 16384, 1024, 896, 4);
    // GEMM2: 16384x512, K=1024 -> BM=128 keeps grid at 128x2 = 256 blocks
    gemm_pipe<128, 256><<<256, 512, 0, stream>>>(h1, Wt1, b1, h2, 16384, 512, 1024, 2);
    gemm3_final<<<256, 256, 0, stream>>>(h2, Wt2, b2, Wo, bo, lg, out);
}

// Round 2
// 497.353 us; speedup vs baseline: 1.0015x; 1.0015x over previous
//
#include <hip/hip_runtime.h>
#include <math.h>

// ---------------------------------------------------------------------------
// DeepFM on MI355X, round 5.
// Measurement model (R0/R1 evidence): timed iteration contains 2x 1.33GB
// workspace poison fills (~408us) + our ~85-90us of kernels. Optimizing the
// kernel residual only.
// Pipeline: [prep: wtrans x3 + gather+FM] -> [gemm_pipe<128,256> GEMM1]
//           -> [gemm_pipe<128,256> GEMM2] -> [GEMM3 64x256 fused head]
// gemm_pipe (R2 synthesis of R0 occupancy + R1 pipeline):
//   256 threads, 2x2 waves, per-wave 64x128 (4x8 MFMA 16x16x32), BK=32,
//   3 LDS buffers (72 KB -> 2 blocks/CU), prefetch distance 2, counted
//   vmcnt (2*LPT / LPT / 0 -- never 0 in steady state), raw s_barrier,
//   LDS slot-XOR swizzle (byte ^= (row&3)<<4) applied BOTH sides:
//   pre-swizzled global source for global_load_lds + swizzled ds_read.
// Workspace layout (bytes):
//   h0  @ 0        : bf16 [16384 x 896] (29,360,128); reused for h2 bf16 [16384 x 512]
//   h1  @ 29360128 : bf16 [16384 x 1024] (33,554,432)
//   Wt0 @ 62914560 : bf16 [1024 x 896]
//   Wt1 @ 64749568 : bf16 [512 x 1024]
//   Wt2 @ 65798144 : bf16 [256 x 512]
//   lg  @ 66060288 : f32 [16384]
// ---------------------------------------------------------------------------

typedef __attribute__((ext_vector_type(8))) short shortx8;
typedef __attribute__((ext_vector_type(4))) float floatx4;

#define AS1 __attribute__((address_space(1)))
#define AS3 __attribute__((address_space(3)))

__device__ __forceinline__ void load_lds_16(const void* g, void* l) {
    __builtin_amdgcn_global_load_lds((AS1 void*)g, (AS3 void*)l, 16, 0, 0);
}

__device__ __forceinline__ unsigned short f2bf(float x) {
    union { float f; unsigned int u; } v; v.f = x;
    unsigned int r = v.u + 0x7fffu + ((v.u >> 16) & 1u);
    return (unsigned short)(r >> 16);
}

template<int N>
__device__ __forceinline__ void waitvm() {
    asm volatile("s_waitcnt vmcnt(%0)" :: "n"(N) : "memory");
}

// Raw barrier: no implicit vmcnt(0)/lgkmcnt(0) drain (unlike __syncthreads).
__device__ __forceinline__ void bar() {
    asm volatile("" ::: "memory");
    __builtin_amdgcn_s_barrier();
    asm volatile("" ::: "memory");
}

// ---------------------------------------------------------------------------
// Prep kernel: blockIdx ranges dispatch to gather+FM or one of 3 wtrans tiles.
//   [0, 4096)            : gather+FM (wave per batch row)
//   [4096, 4992)         : wtrans W0 -> Wt0 [1024 x 896], grid 28 x 32
//   [4992, 5504)         : wtrans W1 -> Wt1 [512 x 1024], grid 32 x 16
//   [5504, 5632)         : wtrans W2 -> Wt2 [256 x 512],  grid 16 x 8
// ---------------------------------------------------------------------------
__device__ __forceinline__
void wtrans_tile(const float* __restrict__ W, unsigned short* __restrict__ Wt,
                 int K, int N, int Kpad, int bx, int by, int tid)
{
    __shared__ float tile[32][33];
    const int k0 = bx * 32, n0 = by * 32;
    const int tx = tid & 31, ty = tid >> 5;
#pragma unroll
    for (int i = 0; i < 32; i += 8) {
        int k = k0 + ty + i;
        tile[ty + i][tx] = (k < K) ? W[(size_t)k * N + (n0 + tx)] : 0.f;
    }
    __syncthreads();
#pragma unroll
    for (int i = 0; i < 32; i += 8) {
        int n = n0 + ty + i, kk = k0 + tx;
        Wt[(size_t)n * Kpad + kk] = f2bf(tile[tx][ty + i]);
    }
}

__global__ __launch_bounds__(256)
void prep(const int* __restrict__ xs, const float* __restrict__ xd,
          const float* __restrict__ emb, const float* __restrict__ lint,
          const float* __restrict__ W0, const float* __restrict__ W1,
          const float* __restrict__ W2,
          unsigned short* __restrict__ h0, float* __restrict__ lg,
          unsigned short* __restrict__ Wt0, unsigned short* __restrict__ Wt1,
          unsigned short* __restrict__ Wt2)
{
    const int bid = blockIdx.x;
    const int tid = threadIdx.x;

    if (bid >= 4096) {
        int t = bid - 4096;
        if (t < 896)       wtrans_tile(W0, Wt0, 845, 1024, 896, t % 28, t / 28, tid);
        else if (t < 1408) wtrans_tile(W1, Wt1, 1024, 512, 1024, (t - 896) % 32, (t - 896) / 32, tid);
        else               wtrans_tile(W2, Wt2, 512, 256, 512, (t - 1408) % 16, (t - 1408) / 16, tid);
        return;
    }

    const int lane = tid & 63;
    const int wave = tid >> 6;
    const int b = bid * 4 + wave;

    int idx = 0; float linv = 0.f;
    if (lane < 26) {
        idx = xs[b * 26 + lane];
        linv = lint[(size_t)lane * 100000 + idx];
    }
    const int d = lane & 31;
    const int half = lane >> 5;
    float s = 0.f, sq = 0.f;
    unsigned short* hrow = h0 + (size_t)b * 896;
#pragma unroll
    for (int it = 0; it < 13; ++it) {
        int f = it * 2 + half;
        int fidx = __shfl(idx, f);
        float v = emb[((size_t)f * 100000 + (size_t)fidx) * 32 + d];
        s += v; sq += v * v;
        hrow[f * 32 + d] = f2bf(v);
    }
    s += __shfl_xor(s, 32);
    float t = 0.25f * s * s - 0.5f * sq + linv;
#pragma unroll
    for (int off = 32; off >= 1; off >>= 1) t += __shfl_xor(t, off);
    if (lane == 0) lg[b] = t;

    // cols 832..844 dense, 845..895 zero: lanes 13..63 cover 845..895 exactly
    if (lane < 13) hrow[832 + lane] = f2bf(xd[b * 13 + lane]);
    else           hrow[832 + lane] = 0;
}

// ---------------------------------------------------------------------------
// Pipelined GEMM: Y[M,N] = relu(X@Wt^T + bias), bf16 in/out, f32 acc.
// 256 threads = 4 waves (2M x 2N), per-wave (BM/2) x (BN/2), BK=32.
// 3 LDS buffers (tile t -> buf t%3), prefetch distance 2:
//   iter t: [STAGE(t+2)] -> waitvm(2*LPT | LPT | 0) -> bar()
//           -> swizzled ds_read frags -> MFMA -> bar()
// Ledger: reads of buf t%3 complete (lgkm, consumed by MFMA) before iter t's
// trailing bar; that buf is next written by STAGE(t+3), issued at iter t+1
// after the bar. vmcnt retires in issue order, so waitvm(2*LPT) == "tile t
// fully landed" (m135).
// Swizzle: rows of 32 bf16 = 64B = 4x16B slots; stored slot = logical ^
// (row&3). global_load_lds writes linearly, so the permutation is applied to
// the GLOBAL source k-offset; ds_read applies the same XOR (involution).
// ---------------------------------------------------------------------------
template<int BM, int BN>
__global__ __launch_bounds__(256, 2)
void gemm_pipe(const unsigned short* __restrict__ X,
               const unsigned short* __restrict__ Wt,
               const float* __restrict__ bias,
               unsigned short* __restrict__ Y,
               int M, int N, int K)
{
    constexpr int CA  = BM / 64;        // A staging loads/thread/tile
    constexpr int CB  = BN / 64;        // B staging loads/thread/tile
    constexpr int LPT = CA + CB;
    constexpr int MR  = BM / 32;        // 16-row frags per wave (2 M-waves)
    constexpr int NR  = BN / 32;        // 16-col frags per wave (2 N-waves)

    __shared__ alignas(16) unsigned short As[3][BM * 32];
    __shared__ alignas(16) unsigned short Bs[3][BN * 32];

    const int tid   = threadIdx.x;
    const int lane  = tid & 63;
    const int wave  = tid >> 6;
    const int lrow  = lane & 15;
    const int lquad = lane >> 4;
    const int wm = (wave & 1) * (BM / 2);
    const int wn = (wave >> 1) * (BN / 2);
    const int bm = blockIdx.x * BM;
    const int bn = blockIdx.y * BN;

    floatx4 acc[MR][NR];
    const floatx4 z4 = {0.f, 0.f, 0.f, 0.f};
#pragma unroll
    for (int i = 0; i < MR; ++i)
#pragma unroll
        for (int j = 0; j < NR; ++j) acc[i][j] = z4;

    const int NT = K >> 5;   // K-tiles of 32

    auto STAGE = [&](int tt) {
        const int k0 = tt << 5;
        unsigned short* a_dst = As[tt % 3];
        unsigned short* b_dst = Bs[tt % 3];
#pragma unroll
        for (int q = 0; q < CA; ++q) {
            int c = tid + q * 256;
            int row = c >> 2, sl = c & 3;
            load_lds_16(X + (size_t)(bm + row) * K + (k0 + ((sl ^ (row & 3)) << 3)),
                        a_dst + c * 8);
        }
#pragma unroll
        for (int q = 0; q < CB; ++q) {
            int c = tid + q * 256;
            int row = c >> 2, sl = c & 3;
            load_lds_16(Wt + (size_t)(bn + row) * K + (k0 + ((sl ^ (row & 3)) << 3)),
                        b_dst + c * 8);
        }
    };

    // prologue: tiles 0,1 in flight
    STAGE(0); STAGE(1);

    // swizzled ds_read base offsets (elements); wm, wn, i*16 all ≡ 0 mod 4
    const int abase = (wm + lrow) * 32 + ((lquad ^ (lrow & 3)) << 3);
    const int bbase = (wn + lrow) * 32 + ((lquad ^ (lrow & 3)) << 3);

    for (int t = 0; t < NT; ++t) {
        const int cur = t % 3;
        if (t + 2 < NT)      { STAGE(t + 2); waitvm<2 * LPT>(); }
        else if (t + 1 < NT) waitvm<LPT>();
        else                 waitvm<0>();
        bar();

        shortx8 a[MR], b[NR];
#pragma unroll
        for (int i = 0; i < MR; ++i)
            a[i] = *(const shortx8*)(&As[cur][abase + i * 512]);
#pragma unroll
        for (int j = 0; j < NR; ++j)
            b[j] = *(const shortx8*)(&Bs[cur][bbase + j * 512]);

        __builtin_amdgcn_s_setprio(1);
#pragma unroll
        for (int i = 0; i < MR; ++i)
#pragma unroll
            for (int j = 0; j < NR; ++j)
                acc[i][j] = __builtin_amdgcn_mfma_f32_16x16x32_bf16(a[i], b[j], acc[i][j], 0, 0, 0);
        __builtin_amdgcn_s_setprio(0);
        bar();
    }

#pragma unroll
    for (int i = 0; i < MR; ++i) {
        const int row = bm + wm + i * 16 + lquad * 4;
#pragma unroll
        for (int j = 0; j < NR; ++j) {
            const int col = bn + wn + j * 16 + lrow;
            const float bv = bias[col];
#pragma unroll
            for (int r = 0; r < 4; ++r) {
                float v = fmaxf(acc[i][j][r] + bv, 0.f);
                Y[(size_t)(row + r) * N + col] = f2bf(v);
            }
        }
    }
}

// ---------------------------------------------------------------------------
// GEMM3 fused with output head. Block: 64 rows x full N=256 (K=512, BK=32).
// Same both-sides slot-XOR swizzle on As/Bs.
// ---------------------------------------------------------------------------
__global__ __launch_bounds__(256)
void gemm3_final(const unsigned short* __restrict__ X,   // h2 [16384 x 512] bf16
                 const unsigned short* __restrict__ Wt,  // Wt2 [256 x 512] bf16
                 const float* __restrict__ bias,         // b2 [256]
                 const float* __restrict__ Wo,           // [256]
                 const float* __restrict__ bo,           // [1]
                 const float* __restrict__ lg,           // [16384]
                 float* __restrict__ out)                // [16384]
{
    const int K = 512;
    __shared__ alignas(16) unsigned short As[64 * 32];
    __shared__ alignas(16) unsigned short Bs[256 * 32];
    __shared__ float red[4][64];

    const int tid  = threadIdx.x;
    const int lane = tid & 63;
    const int wave = tid >> 6;
    const int bm = blockIdx.x * 64;
    const int wn = wave * 64;
    const int lrow  = lane & 15;
    const int lquad = lane >> 4;

    floatx4 acc[4][4];
    const floatx4 z4 = {0.f, 0.f, 0.f, 0.f};
#pragma unroll
    for (int i = 0; i < 4; ++i)
#pragma unroll
        for (int j = 0; j < 4; ++j) acc[i][j] = z4;

    const int ar = tid >> 2;
    const int asw = ((tid & 3) ^ (ar & 3)) << 3;   // swizzled source k-offset

    for (int k0 = 0; k0 < K; k0 += 32) {
        load_lds_16(X + (size_t)(bm + ar) * K + (k0 + asw), As + (size_t)tid * 8);
#pragma unroll
        for (int q = 0; q < 4; ++q) {
            int c = tid + q * 256;
            int row = c >> 2;
            load_lds_16(Wt + (size_t)row * K + (k0 + (((c & 3) ^ (row & 3)) << 3)),
                        Bs + (size_t)c * 8);
        }
        __syncthreads();

        const int rsw = (lquad ^ (lrow & 3)) << 3;
        shortx8 a[4], b[4];
#pragma unroll
        for (int i = 0; i < 4; ++i)
            a[i] = *(const shortx8*)(As + (i * 16 + lrow) * 32 + rsw);
#pragma unroll
        for (int j = 0; j < 4; ++j)
            b[j] = *(const shortx8*)(Bs + (wn + j * 16 + lrow) * 32 + rsw);
#pragma unroll
        for (int i = 0; i < 4; ++i)
#pragma unroll
            for (int j = 0; j < 4; ++j)
                acc[i][j] = __builtin_amdgcn_mfma_f32_16x16x32_bf16(a[i], b[j], acc[i][j], 0, 0, 0);
        __syncthreads();
    }

    float bv[4], wv[4];
#pragma unroll
    for (int j = 0; j < 4; ++j) {
        int col = wn + j * 16 + lrow;
        bv[j] = bias[col];
        wv[j] = Wo[col];
    }
#pragma unroll
    for (int i = 0; i < 4; ++i) {
#pragma unroll
        for (int r = 0; r < 4; ++r) {
            float p = 0.f;
#pragma unroll
            for (int j = 0; j < 4; ++j) {
                float v = fmaxf(acc[i][j][r] + bv[j], 0.f);
                p += v * wv[j];
            }
            p += __shfl_xor(p, 1);
            p += __shfl_xor(p, 2);
            p += __shfl_xor(p, 4);
            p += __shfl_xor(p, 8);
            if (lrow == 0) red[wave][i * 16 + lquad * 4 + r] = p;
        }
    }
    __syncthreads();
    if (tid < 64) {
        float s = red[0][tid] + red[1][tid] + red[2][tid] + red[3][tid];
        float x = s + bo[0] + lg[bm + tid];
        out[bm + tid] = 1.f / (1.f + expf(-x));
    }
}

extern "C" void kernel_launch(void* const* d_in, const int* in_sizes, int n_in,
                              void* d_out, int out_size, void* d_ws, size_t ws_size,
                              hipStream_t stream)
{
    const int*   xs = (const int*)d_in[0];
    const float* xd = (const float*)d_in[1];
    const float* em = (const float*)d_in[2];
    const float* li = (const float*)d_in[3];
    const float* W0 = (const float*)d_in[4];
    const float* b0 = (const float*)d_in[5];
    const float* W1 = (const float*)d_in[6];
    const float* b1 = (const float*)d_in[7];
    const float* W2 = (const float*)d_in[8];
    const float* b2 = (const float*)d_in[9];
    const float* Wo = (const float*)d_in[10];
    const float* bo = (const float*)d_in[11];
    float* out = (float*)d_out;

    char* ws = (char*)d_ws;
    unsigned short* h0  = (unsigned short*)(ws);             // 16384x896 bf16
    unsigned short* h1  = (unsigned short*)(ws + 29360128);  // 16384x1024 bf16
    unsigned short* h2  = (unsigned short*)(ws);             // reuse: 16384x512 bf16
    unsigned short* Wt0 = (unsigned short*)(ws + 62914560);  // 1024x896 bf16
    unsigned short* Wt1 = (unsigned short*)(ws + 64749568);  // 512x1024 bf16
    unsigned short* Wt2 = (unsigned short*)(ws + 65798144);  // 256x512 bf16
    float*          lg  = (float*)(ws + 66060288);           // 16384 f32

    prep<<<5632, 256, 0, stream>>>(xs, xd, em, li, W0, W1, W2, h0, lg, Wt0, Wt1, Wt2);

    // GEMM1: 16384x1024, K=896 -> grid 128x4 = 512 blocks, 2/CU.
    // Blocks sharing an A panel (same x, diff y) have linear ids x+128y ->
    // same id%8 -> same XCD: A panel L2-reuse is already optimal, no swizzle.
    gemm_pipe<128, 256><<<dim3(128, 4), 256, 0, stream>>>(h0, Wt0, b0, h1, 16384, 1024, 896);
    // GEMM2: 16384x512, K=1024 -> grid 128x2 = 256 blocks.
    gemm_pipe<128, 256><<<dim3(128, 2), 256, 0, stream>>>(h1, Wt1, b1, h2, 16384, 512, 1024);
    gemm3_final<<<256, 256, 0, stream>>>(h2, Wt2, b2, Wo, bo, lg, out);
}